// Round 1
// baseline (77.688 us; speedup 1.0000x reference)
//
#include <hip/hip_runtime.h>

// Fused: depthwise(1x3, 64ch) -> pair-sum (64->32ch) -> conv3x3 (32->64ch)
// x:      (1,64,56,56) f32
// w_conv: (64,32,3,3,1) f32  -> effective (64,32,3,3)
// w_dw:   (64,3,1) f32       -> effective (64,3) per-channel 1x3 taps
// out:    (1,64,56,56) f32
//
// Grid: (56 rows, 4 out-channel-groups of 16). Block: 256 threads.
// Per block: stage weights + fused t5 tile (3 rows x 32ch x 58w) in LDS,
// then each thread computes 4 consecutive-w outputs via register sliding window.

#define HH 56
#define WW 56
#define CMID 32
#define OG 16      // out channels per block
#define T5STR 60   // LDS row stride for t5 (60*4B = 240B, 16B-aligned steps)
#define WCSTR 292  // per-out-channel weight stride in LDS (292 % 32 == 4 -> no bank aliasing)

__global__ __launch_bounds__(256) void fused_dw_sum_conv(
    const float* __restrict__ x,
    const float* __restrict__ wc,
    const float* __restrict__ wd,
    float* __restrict__ out)
{
    __shared__ float sdw[64 * 3];
    __shared__ float swc[OG * WCSTR];
    __shared__ __align__(16) float st5[3 * CMID * T5STR];

    const int tid = threadIdx.x;
    const int h   = blockIdx.x;   // output row
    const int og  = blockIdx.y;   // out-channel group

    // ---- stage weights ----
    if (tid < 64 * 3) sdw[tid] = wd[tid];
    for (int i = tid; i < OG * 288; i += 256) {
        int ol = i / 288;
        int r  = i - ol * 288;
        swc[ol * WCSTR + r] = wc[(og * OG + ol) * 288 + r];
    }
    __syncthreads();

    // ---- phase 1: fused depthwise + pair-sum into LDS t5 tile ----
    // t5 logical coords: rows hr = h-1+r (r=0..2), cc in [0,32), w' in [-1,56]
    // stored at st5[(r*CMID+cc)*T5STR + (w'+1)]; out-of-range -> 0 (conv padding)
    for (int idx = tid; idx < 3 * CMID * 58; idx += 256) {
        int r   = idx / (CMID * 58);
        int rem = idx - r * (CMID * 58);
        int cc  = rem / 58;
        int ws  = rem - cc * 58;
        int wp  = ws - 1;         // t5 w coordinate
        int hr  = h - 1 + r;
        float val = 0.f;
        if ((unsigned)hr < HH && (unsigned)wp < WW) {
            const float* x0 = x + (2 * cc) * (HH * WW) + hr * WW;
            const float* x1 = x0 + HH * WW;
            const float* d0 = sdw + (2 * cc) * 3;
            const float* d1 = d0 + 3;
            #pragma unroll
            for (int k = 0; k < 3; ++k) {
                int wx = wp - 1 + k;
                if ((unsigned)wx < WW)
                    val += x0[wx] * d0[k] + x1[wx] * d1[k];
            }
        }
        st5[(r * CMID + cc) * T5STR + ws] = val;
    }
    __syncthreads();

    // ---- phase 2: 3x3 conv, 4 outputs (consecutive w) per thread ----
    // 16 out-channels x 14 w-tiles = 224 work items
    if (tid < OG * 14) {
        int ol = tid / 14;
        int wt = tid - ol * 14;
        int w0 = wt * 4;
        float acc0 = 0.f, acc1 = 0.f, acc2 = 0.f, acc3 = 0.f;
        const float* wrow = swc + ol * WCSTR;
        for (int cc = 0; cc < CMID; ++cc) {
            #pragma unroll
            for (int dh = 0; dh < 3; ++dh) {
                const float* trow = st5 + (dh * CMID + cc) * T5STR + w0;
                float4 a = *(const float4*)trow;        // 16B-aligned
                float2 b = *(const float2*)(trow + 4);  // 16B-aligned
                const float* wv = wrow + cc * 9 + dh * 3;
                float wv0 = wv[0], wv1 = wv[1], wv2 = wv[2];
                acc0 += a.x * wv0 + a.y * wv1 + a.z * wv2;
                acc1 += a.y * wv0 + a.z * wv1 + a.w * wv2;
                acc2 += a.z * wv0 + a.w * wv1 + b.x * wv2;
                acc3 += a.w * wv0 + b.x * wv1 + b.y * wv2;
            }
        }
        int o = og * OG + ol;
        float4 res = {acc0, acc1, acc2, acc3};
        *(float4*)(out + o * (HH * WW) + h * WW + w0) = res;  // 16B-aligned
    }
}

extern "C" void kernel_launch(void* const* d_in, const int* in_sizes, int n_in,
                              void* d_out, int out_size, void* d_ws, size_t ws_size,
                              hipStream_t stream) {
    const float* x  = (const float*)d_in[0];
    const float* wc = (const float*)d_in[1];
    const float* wd = (const float*)d_in[2];
    float* out = (float*)d_out;
    dim3 grid(HH, 64 / OG);  // 56 x 4 = 224 blocks
    fused_dw_sum_conv<<<grid, 256, 0, stream>>>(x, wc, wd, out);
}

// Round 2
// 72.882 us; speedup vs baseline: 1.0659x; 1.0659x over previous
//
#include <hip/hip_runtime.h>

// Fused: depthwise(1x3, 64ch) -> pair-sum (64->32ch) -> conv3x3 (32->64ch)
// x: (1,64,56,56) f32, w_conv: (64,32,3,3,1), w_dw: (64,3,1), out: (1,64,56,56)
//
// Grid (56 rows, 4 og). Block 256.
// Phase 0: stage weights + 3 x-rows (float4 coalesced) into LDS.
// Phase 1: fused depthwise+pair-sum -> st5[3][32][60] in LDS.
// Phase 2: 3x3 conv; thread = (olg 0..7) x (wt 0..6, 8-wide) x (ccq 0..3 in lane
//          bits 0-1); 2 out-ch x 8 w outputs, cc split 4-way, shfl_xor reduce.

#define HH 56
#define WW 56
#define CIN 64
#define CMID 32
#define OG 16
#define T5STR 60   // 16B-aligned row stride
#define WSTR 388   // 32*3*4 + 4 pad: per-ol stride, breaks bank alignment

__global__ __launch_bounds__(256) void fused_dw_sum_conv(
    const float* __restrict__ x,
    const float* __restrict__ wc,
    const float* __restrict__ wd,
    float* __restrict__ out)
{
    __shared__ __align__(16) float sx[3 * CIN * WW];       // 43008 B
    __shared__ __align__(16) float st5[3 * CMID * T5STR];  // 23040 B
    __shared__ __align__(16) float swc[OG * WSTR];         // 24832 B
    __shared__ float sdw[CIN * 3];                         //   768 B

    const int tid = threadIdx.x;
    const int h   = blockIdx.x;
    const int og  = blockIdx.y;

    // ---- phase 0: stage weights + x rows ----
    if (tid < CIN * 3) sdw[tid] = wd[tid];

    for (int i = tid; i < OG * 288; i += 256) {
        int ol  = i / 288;
        int r   = i - ol * 288;        // cc*9 + dh*3 + k
        int cc  = r / 9;
        int rem = r - cc * 9;
        int dh  = rem / 3;
        int k   = rem - dh * 3;
        swc[ol * WSTR + (cc * 3 + dh) * 4 + k] = wc[(og * OG + ol) * 288 + r];
    }

    // x rows h-1..h+1, float4 coalesced: 3*64*14 = 2688 quads
    for (int i = tid; i < 3 * CIN * 14; i += 256) {
        int r  = i / (CIN * 14);
        int hr = h - 1 + r;
        if ((unsigned)hr < HH) {
            int j  = i - r * (CIN * 14);
            int c  = j / 14;
            int wq = j - c * 14;
            ((float4*)sx)[i] = ((const float4*)x)[(c * HH + hr) * 14 + wq];
        }
    }
    __syncthreads();

    // ---- phase 1: t5 = pairsum(depthwise(x)) into LDS ----
    for (int idx = tid; idx < 3 * CMID * 58; idx += 256) {
        int r   = idx / (CMID * 58);
        int rem = idx - r * (CMID * 58);
        int cc  = rem / 58;
        int ws  = rem - cc * 58;       // st5 col = t5_w + 1
        int wp  = ws - 1;
        int hr  = h - 1 + r;
        float val = 0.f;
        if ((unsigned)hr < HH && (unsigned)wp < WW) {
            const float* x0 = sx + (r * CIN + 2 * cc) * WW;
            const float* x1 = x0 + WW;
            const float* d0 = sdw + (2 * cc) * 3;
            #pragma unroll
            for (int k = 0; k < 3; ++k) {
                int wx = wp - 1 + k;
                if ((unsigned)wx < WW)
                    val += x0[wx] * d0[k] + x1[wx] * d0[3 + k];
            }
        }
        st5[(r * CMID + cc) * T5STR + ws] = val;
    }
    __syncthreads();

    // ---- phase 2: 3x3 conv, register-blocked 2 ol x 8 w, cc split by ccq ----
    if (tid < 224) {
        const int ccq  = tid & 3;        // lane bits 0-1 -> shfl_xor reduce
        const int rest = tid >> 2;       // 0..55
        const int olg  = rest / 7;       // 0..7
        const int wt   = rest - olg * 7; // 0..6
        const int w0   = wt * 8;
        const int ol0  = olg * 2;

        float acc0[8] = {0,0,0,0,0,0,0,0};
        float acc1[8] = {0,0,0,0,0,0,0,0};
        const float* wb0 = swc + ol0 * WSTR;
        const float* wb1 = wb0 + WSTR;

        #pragma unroll
        for (int i = 0; i < 8; ++i) {
            int cc = ccq + 4 * i;        // interleaved: ccq lanes hit distinct banks
            #pragma unroll
            for (int dh = 0; dh < 3; ++dh) {
                const float* trow = st5 + (dh * CMID + cc) * T5STR + w0;
                float4 a  = *(const float4*)trow;
                float4 b  = *(const float4*)(trow + 4);
                float2 c2 = *(const float2*)(trow + 8);
                float t[10] = {a.x, a.y, a.z, a.w, b.x, b.y, b.z, b.w, c2.x, c2.y};
                int wi = (cc * 3 + dh) * 4;
                float4 wv0 = *(const float4*)(wb0 + wi);
                float4 wv1 = *(const float4*)(wb1 + wi);
                #pragma unroll
                for (int j = 0; j < 8; ++j) {
                    acc0[j] += t[j] * wv0.x + t[j + 1] * wv0.y + t[j + 2] * wv0.z;
                    acc1[j] += t[j] * wv1.x + t[j + 1] * wv1.y + t[j + 2] * wv1.z;
                }
            }
        }

        // reduce the 4 ccq partial sums (lane bits 0-1)
        #pragma unroll
        for (int j = 0; j < 8; ++j) {
            acc0[j] += __shfl_xor(acc0[j], 1);
            acc0[j] += __shfl_xor(acc0[j], 2);
            acc1[j] += __shfl_xor(acc1[j], 1);
            acc1[j] += __shfl_xor(acc1[j], 2);
        }

        if (ccq == 0) {
            int o0 = og * OG + ol0;
            float* p0 = out + (o0 * HH + h) * WW + w0;
            float* p1 = p0 + HH * WW;
            *(float4*)(p0)     = make_float4(acc0[0], acc0[1], acc0[2], acc0[3]);
            *(float4*)(p0 + 4) = make_float4(acc0[4], acc0[5], acc0[6], acc0[7]);
            *(float4*)(p1)     = make_float4(acc1[0], acc1[1], acc1[2], acc1[3]);
            *(float4*)(p1 + 4) = make_float4(acc1[4], acc1[5], acc1[6], acc1[7]);
        }
    }
}

extern "C" void kernel_launch(void* const* d_in, const int* in_sizes, int n_in,
                              void* d_out, int out_size, void* d_ws, size_t ws_size,
                              hipStream_t stream) {
    const float* x  = (const float*)d_in[0];
    const float* wc = (const float*)d_in[1];
    const float* wd = (const float*)d_in[2];
    float* out = (float*)d_out;
    dim3 grid(HH, CIN / OG);  // 56 x 4 = 224 blocks
    fused_dw_sum_conv<<<grid, 256, 0, stream>>>(x, wc, wd, out);
}

// Round 3
// 68.843 us; speedup vs baseline: 1.1285x; 1.0587x over previous
//
#include <hip/hip_runtime.h>

// Fused: depthwise(1x3, 64ch) -> pair-sum (64->32ch) -> conv3x3 (32->64ch)
// x: (1,64,56,56) f32, w_conv: (64,32,3,3,1), w_dw: (64,3,1), out: (1,64,56,56)
//
// Grid (56 rows, 4 og of 16 out-ch). Block 256. All LDS strides chosen so every
// wave LDS access is <=2-way bank aliased (free per m136).
// Phase 0: stage weights (padded slots), packed dw taps, zero-padded x rows.
// Phase 1: vectorized fused depthwise+pair-sum -> st5[96][68], 4 outputs/thread,
//          no bounds checks (borders pre-zeroed, OOB rows zero-staged).
// Phase 2: 3x3 conv, 2 out-ch x 8 w per thread, cc split 4-way (lane bits 0-1),
//          shfl_xor reduce, float4 stores.

#define HH 56
#define WW 56
#define CIN 64
#define CMID 32
#define OG 16
#define SXSTR 68   // 68 % 32 == 4: adjacent rows offset 4 banks; 16B-aligned rows
#define T5STR 68
#define WSTR 388   // 32*3*4 + 4 pad

__global__ __launch_bounds__(256) void fused_dw_sum_conv(
    const float* __restrict__ x,
    const float* __restrict__ wc,
    const float* __restrict__ wd,
    float* __restrict__ out)
{
    __shared__ __align__(16) float sx[3 * CIN * SXSTR];    // 52224 B
    __shared__ __align__(16) float st5[3 * CMID * T5STR];  // 26112 B
    __shared__ __align__(16) float swc[OG * WSTR];         // 24832 B
    __shared__ __align__(16) float sdwp[CMID * 8];         //  1024 B

    const int tid = threadIdx.x;
    const int h   = blockIdx.x;
    const int og  = blockIdx.y;

    // ---- phase 0a: x rows h-1..h+1 -> sx[r][c][2..57] (issue global loads first)
    for (int i = tid; i < 3 * CIN * 14; i += 256) {
        int r  = i / (CIN * 14);
        int j  = i - r * (CIN * 14);
        int c  = j / 14;
        int jq = j - c * 14;
        int hr = h - 1 + r;
        float4 v = make_float4(0.f, 0.f, 0.f, 0.f);
        if ((unsigned)hr < HH)
            v = *(const float4*)(x + c * (HH * WW) + hr * WW + 4 * jq);
        float* dst = sx + (r * CIN + c) * SXSTR + 2 + 4 * jq;  // 8B-aligned
        *(float2*)dst       = make_float2(v.x, v.y);
        *(float2*)(dst + 2) = make_float2(v.z, v.w);
    }

    // ---- phase 0b: packed dw taps: sdwp[cc][0..5] = wd[6cc .. 6cc+5]
    if (tid < CMID) {
        #pragma unroll
        for (int k = 0; k < 6; ++k) sdwp[tid * 8 + k] = wd[tid * 6 + k];
    }

    // ---- phase 0c: conv weights into padded 4-float slots
    for (int i = tid; i < OG * 288; i += 256) {
        int ol  = i / 288;
        int r   = i - ol * 288;       // cc*9 + dh*3 + k
        int cc  = r / 9;
        int rem = r - cc * 9;
        int dh  = rem / 3;
        int k   = rem - dh * 3;
        swc[ol * WSTR + (cc * 3 + dh) * 4 + k] = wc[(og * OG + ol) * 288 + r];
    }

    // ---- phase 0d: zero sx borders: cols 0,1 and 58..61 per row (3*192 items)
    for (int i = tid; i < 576; i += 256) {
        int row   = i / 3;
        int which = i - row * 3;
        int col   = (which == 0) ? 0 : (which == 1 ? 58 : 60);
        *(float2*)(sx + row * SXSTR + col) = make_float2(0.f, 0.f);
    }
    __syncthreads();

    // ---- phase 1: t5 = pairsum(depthwise(x)), 4 outputs per item, vectorized
    // item = (r, cc, wq), wq in [0,15): outputs st5 cols 4wq..4wq+3
    for (int idx = tid; idx < 3 * CMID * 15; idx += 256) {
        int r   = idx / (CMID * 15);
        int rem = idx - r * (CMID * 15);
        int cc  = rem / 15;
        int wq  = rem - cc * 15;
        int ws0 = 4 * wq;
        const float* x0 = sx + (r * CIN + 2 * cc) * SXSTR + ws0;
        const float* x1 = x0 + SXSTR;
        float4 a0 = *(const float4*)x0;
        float2 b0 = *(const float2*)(x0 + 4);
        float4 a1 = *(const float4*)x1;
        float2 b1 = *(const float2*)(x1 + 4);
        float4 dA = *(const float4*)(sdwp + cc * 8);      // d0[0..2], d1[0]
        float2 dB = *(const float2*)(sdwp + cc * 8 + 4);  // d1[1..2]
        float t0[6] = {a0.x, a0.y, a0.z, a0.w, b0.x, b0.y};
        float t1[6] = {a1.x, a1.y, a1.z, a1.w, b1.x, b1.y};
        float v[4];
        #pragma unroll
        for (int q = 0; q < 4; ++q)
            v[q] = t0[q] * dA.x + t0[q + 1] * dA.y + t0[q + 2] * dA.z
                 + t1[q] * dA.w + t1[q + 1] * dB.x + t1[q + 2] * dB.y;
        if (wq == 0)  v[0] = 0.f;                    // wp = -1 halo
        if (wq == 14) { v[1] = 0.f; v[2] = 0.f; v[3] = 0.f; }  // wp >= 56 halo
        *(float4*)(st5 + (r * CMID + cc) * T5STR + ws0) =
            make_float4(v[0], v[1], v[2], v[3]);
    }
    __syncthreads();

    // ---- phase 2: 3x3 conv, 2 ol x 8 w per thread, cc split by ccq ----
    if (tid < 224) {
        const int ccq  = tid & 3;        // lane bits 0-1 -> shfl_xor reduce
        const int rest = tid >> 2;
        const int olg  = rest / 7;       // 0..7
        const int wt   = rest - olg * 7; // 0..6
        const int w0   = wt * 8;
        const int ol0  = olg * 2;

        float acc0[8] = {0, 0, 0, 0, 0, 0, 0, 0};
        float acc1[8] = {0, 0, 0, 0, 0, 0, 0, 0};
        const float* wb0 = swc + ol0 * WSTR;
        const float* wb1 = wb0 + WSTR;

        #pragma unroll
        for (int i = 0; i < 8; ++i) {
            int cc = ccq + 4 * i;  // ccq lanes: adjacent st5 rows -> +4 banks, disjoint
            #pragma unroll
            for (int dh = 0; dh < 3; ++dh) {
                const float* trow = st5 + (dh * CMID + cc) * T5STR + w0;
                float4 a  = *(const float4*)trow;
                float4 b  = *(const float4*)(trow + 4);
                float2 c2 = *(const float2*)(trow + 8);
                float t[10] = {a.x, a.y, a.z, a.w, b.x, b.y, b.z, b.w, c2.x, c2.y};
                int wi = (cc * 3 + dh) * 4;
                float4 wv0 = *(const float4*)(wb0 + wi);
                float4 wv1 = *(const float4*)(wb1 + wi);
                #pragma unroll
                for (int j = 0; j < 8; ++j) {
                    acc0[j] += t[j] * wv0.x + t[j + 1] * wv0.y + t[j + 2] * wv0.z;
                    acc1[j] += t[j] * wv1.x + t[j + 1] * wv1.y + t[j + 2] * wv1.z;
                }
            }
        }

        #pragma unroll
        for (int j = 0; j < 8; ++j) {
            acc0[j] += __shfl_xor(acc0[j], 1);
            acc0[j] += __shfl_xor(acc0[j], 2);
            acc1[j] += __shfl_xor(acc1[j], 1);
            acc1[j] += __shfl_xor(acc1[j], 2);
        }

        if (ccq == 0) {
            int o0 = og * OG + ol0;
            float* p0 = out + (o0 * HH + h) * WW + w0;
            float* p1 = p0 + HH * WW;
            *(float4*)(p0)     = make_float4(acc0[0], acc0[1], acc0[2], acc0[3]);
            *(float4*)(p0 + 4) = make_float4(acc0[4], acc0[5], acc0[6], acc0[7]);
            *(float4*)(p1)     = make_float4(acc1[0], acc1[1], acc1[2], acc1[3]);
            *(float4*)(p1 + 4) = make_float4(acc1[4], acc1[5], acc1[6], acc1[7]);
        }
    }
}

extern "C" void kernel_launch(void* const* d_in, const int* in_sizes, int n_in,
                              void* d_out, int out_size, void* d_ws, size_t ws_size,
                              hipStream_t stream) {
    const float* x  = (const float*)d_in[0];
    const float* wc = (const float*)d_in[1];
    const float* wd = (const float*)d_in[2];
    float* out = (float*)d_out;
    dim3 grid(HH, CIN / OG);  // 56 x 4 = 224 blocks
    fused_dw_sum_conv<<<grid, 256, 0, stream>>>(x, wc, wd, out);
}

// Round 5
// 66.106 us; speedup vs baseline: 1.1752x; 1.0414x over previous
//
#include <hip/hip_runtime.h>

// Fused: depthwise(1x3, 64ch) -> pair-sum (64->32ch) -> conv3x3 (32->64ch)
// x: (1,64,56,56) f32, w_conv: (64,32,3,3,1), w_dw: (64,3,1), out: (1,64,56,56)
//
// Grid (56 rows, 4 og of 16 out-ch). Block 256. Single-barrier structure:
// Phase A: stage conv weights into padded LDS slots; compute t5 tile
//          (3 rows x 32 ch x 56+halo) DIRECTLY from global x in registers
//          (x is L2/L3-resident; dw taps read as float2 broadcasts), write
//          st5[96][68] to LDS. No sx staging buffer, no second barrier.
// Phase B: 3x3 conv, 2 out-ch x 8 w per thread, cc split 4-way (lane bits
//          0-1), shfl_xor reduce, float4 stores. (Unchanged, conflict-free.)

#define HH 56
#define WW 56
#define CIN 64
#define CMID 32
#define OG 16
#define CHW (HH * WW)
#define T5STR 68   // 68 % 32 == 4: adjacent rows offset 4 banks; 16B-aligned
#define WSTR 388   // 32*3*4 + 4 pad

__global__ __launch_bounds__(256) void fused_dw_sum_conv(
    const float* __restrict__ x,
    const float* __restrict__ wc,
    const float* __restrict__ wd,
    float* __restrict__ out)
{
    __shared__ __align__(16) float st5[3 * CMID * T5STR];  // 26112 B
    __shared__ __align__(16) float swc[OG * WSTR];         // 24832 B

    const int tid = threadIdx.x;
    const int h   = blockIdx.x;
    const int og  = blockIdx.y;

    // ---- phase A1: conv weights into padded 4-float slots ----
    for (int i = tid; i < OG * 288; i += 256) {
        int ol  = i / 288;
        int r   = i - ol * 288;       // cc*9 + dh*3 + k
        int cc  = r / 9;
        int rem = r - cc * 9;
        int dh  = rem / 3;
        int k   = rem - dh * 3;
        swc[ol * WSTR + (cc * 3 + dh) * 4 + k] = wc[(og * OG + ol) * 288 + r];
    }

    // ---- phase A2: t5 = pairsum(depthwise(x)) direct from global ----
    // item = (r, cc, wq), wq in [0,15): st5 cols 4wq..4wq+3. 1440 items.
    #pragma unroll
    for (int k = 0; k < 6; ++k) {
        int idx = tid + k * 256;
        if (idx < 3 * CMID * 15) {
            int r   = idx / (CMID * 15);
            int rem = idx - r * (CMID * 15);
            int cc  = rem / 15;
            int wq  = rem - cc * 15;
            int ws0 = 4 * wq;
            int hr  = h - 1 + r;
            float4 v4 = make_float4(0.f, 0.f, 0.f, 0.f);
            if ((unsigned)hr < HH) {
                const float* p0 = x + (2 * cc) * CHW + hr * WW;
                const float* p1 = p0 + CHW;
                // clamped addresses (always in-bounds), zero-select after
                int lcol = (wq == 0)  ? 0  : ws0 - 2;   // 8B-aligned
                int mcol = (wq == 14) ? 48 : ws0;       // 16B-aligned
                float2 l0 = *(const float2*)(p0 + lcol);
                float2 l1 = *(const float2*)(p1 + lcol);
                float4 m0 = *(const float4*)(p0 + mcol);
                float4 m1 = *(const float4*)(p1 + mcol);
                if (wq == 0)  { l0 = make_float2(0.f, 0.f); l1 = make_float2(0.f, 0.f); }
                if (wq == 14) { m0 = make_float4(0.f, 0.f, 0.f, 0.f);
                                m1 = make_float4(0.f, 0.f, 0.f, 0.f); }
                // dw taps for channels 2cc, 2cc+1: wd[6cc .. 6cc+5] (L2 broadcast)
                const float* dwp = wd + 6 * cc;
                float2 dA = *(const float2*)(dwp);      // d0[0], d0[1]
                float2 dBp = *(const float2*)(dwp + 2); // d0[2], d1[0]
                float2 dC = *(const float2*)(dwp + 4);  // d1[1], d1[2]
                float t0[6] = {l0.x, l0.y, m0.x, m0.y, m0.z, m0.w};
                float t1[6] = {l1.x, l1.y, m1.x, m1.y, m1.z, m1.w};
                float v[4];
                #pragma unroll
                for (int q = 0; q < 4; ++q)
                    v[q] = t0[q] * dA.x + t0[q + 1] * dA.y + t0[q + 2] * dBp.x
                         + t1[q] * dBp.y + t1[q + 1] * dC.x + t1[q + 2] * dC.y;
                if (wq == 0)  v[0] = 0.f;                              // wp = -1
                if (wq == 14) { v[1] = 0.f; v[2] = 0.f; v[3] = 0.f; }  // wp >= 56
                v4 = make_float4(v[0], v[1], v[2], v[3]);
            }
            *(float4*)(st5 + (r * CMID + cc) * T5STR + ws0) = v4;
        }
    }
    __syncthreads();

    // ---- phase B: 3x3 conv, 2 ol x 8 w per thread, cc split by ccq ----
    if (tid < 224) {
        const int ccq  = tid & 3;        // lane bits 0-1 -> shfl_xor reduce
        const int rest = tid >> 2;
        const int olg  = rest / 7;       // 0..7
        const int wt   = rest - olg * 7; // 0..6
        const int w0   = wt * 8;
        const int ol0  = olg * 2;

        float acc0[8] = {0, 0, 0, 0, 0, 0, 0, 0};
        float acc1[8] = {0, 0, 0, 0, 0, 0, 0, 0};
        const float* wb0 = swc + ol0 * WSTR;
        const float* wb1 = wb0 + WSTR;

        #pragma unroll
        for (int i = 0; i < 8; ++i) {
            int cc = ccq + 4 * i;  // ccq lanes: adjacent st5 rows -> +4 banks
            #pragma unroll
            for (int dh = 0; dh < 3; ++dh) {
                const float* trow = st5 + (dh * CMID + cc) * T5STR + w0;
                float4 a  = *(const float4*)trow;
                float4 b  = *(const float4*)(trow + 4);
                float2 c2 = *(const float2*)(trow + 8);
                float t[10] = {a.x, a.y, a.z, a.w, b.x, b.y, b.z, b.w, c2.x, c2.y};
                int wi = (cc * 3 + dh) * 4;
                float4 wv0 = *(const float4*)(wb0 + wi);
                float4 wv1 = *(const float4*)(wb1 + wi);
                #pragma unroll
                for (int j = 0; j < 8; ++j) {
                    acc0[j] += t[j] * wv0.x + t[j + 1] * wv0.y + t[j + 2] * wv0.z;
                    acc1[j] += t[j] * wv1.x + t[j + 1] * wv1.y + t[j + 2] * wv1.z;
                }
            }
        }

        #pragma unroll
        for (int j = 0; j < 8; ++j) {
            acc0[j] += __shfl_xor(acc0[j], 1);
            acc0[j] += __shfl_xor(acc0[j], 2);
            acc1[j] += __shfl_xor(acc1[j], 1);
            acc1[j] += __shfl_xor(acc1[j], 2);
        }

        if (ccq == 0) {
            int o0 = og * OG + ol0;
            float* p0 = out + (o0 * HH + h) * WW + w0;
            float* p1 = p0 + CHW;
            *(float4*)(p0)     = make_float4(acc0[0], acc0[1], acc0[2], acc0[3]);
            *(float4*)(p0 + 4) = make_float4(acc0[4], acc0[5], acc0[6], acc0[7]);
            *(float4*)(p1)     = make_float4(acc1[0], acc1[1], acc1[2], acc1[3]);
            *(float4*)(p1 + 4) = make_float4(acc1[4], acc1[5], acc1[6], acc1[7]);
        }
    }
}

extern "C" void kernel_launch(void* const* d_in, const int* in_sizes, int n_in,
                              void* d_out, int out_size, void* d_ws, size_t ws_size,
                              hipStream_t stream) {
    const float* x  = (const float*)d_in[0];
    const float* wc = (const float*)d_in[1];
    const float* wd = (const float*)d_in[2];
    float* out = (float*)d_out;
    dim3 grid(HH, CIN / OG);  // 56 x 4 = 224 blocks
    fused_dw_sum_conv<<<grid, 256, 0, stream>>>(x, wc, wd, out);
}

// Round 8
// 63.821 us; speedup vs baseline: 1.2173x; 1.0358x over previous
//
#include <hip/hip_runtime.h>

// Fused: depthwise(1x3, 64ch) -> pair-sum (64->32ch) -> conv3x3 (32->64ch)
// x: (1,64,56,56) f32, w_conv: (64,32,3,3,1), w_dw: (64,3,1), out: (1,64,56,56)
//
// Grid (56 rows, 4 og of 16 out-ch). Block 256. Single barrier.
// Issue-early/compute-late (T14): all A2 x-loads + dw-tap loads are issued
// into registers FIRST; the A1 weight staging (float4 global loads + LDS
// scatter) executes under that latency; then A2 computes t5 and writes
// st5[96][68]; barrier; phase B 3x3 conv (unchanged, conflict-free).

#define HH 56
#define WW 56
#define CIN 64
#define CMID 32
#define OG 16
#define CHW (HH * WW)
#define T5STR 68   // 68 % 32 == 4: adjacent rows offset 4 banks; 16B-aligned
#define WSTR 388   // 32*3*4 + 4 pad

__global__ __launch_bounds__(256) void fused_dw_sum_conv(
    const float* __restrict__ x,
    const float* __restrict__ wc,
    const float* __restrict__ wd,
    float* __restrict__ out)
{
    __shared__ __align__(16) float st5[3 * CMID * T5STR];  // 26112 B
    __shared__ __align__(16) float swc[OG * WSTR];         // 24832 B

    const int tid = threadIdx.x;
    const int h   = blockIdx.x;
    const int og  = blockIdx.y;

    // ---- stage 1: ISSUE all A2 global loads into registers ----
    // item = (r, cc, wq), idx = tid + 256k; r = idx/480, cc = (idx%480)/15.
    float2 L0[6], L1[6], TA[6], TB[6], TC[6];
    float4 M0[6], M1[6];
    #pragma unroll
    for (int k = 0; k < 6; ++k) {
        L0[k] = make_float2(0.f, 0.f); L1[k] = make_float2(0.f, 0.f);
        M0[k] = make_float4(0.f, 0.f, 0.f, 0.f);
        M1[k] = make_float4(0.f, 0.f, 0.f, 0.f);
        int idx = tid + k * 256;
        if (idx < 3 * CMID * 15) {
            int r   = idx / (CMID * 15);
            int rem = idx - r * (CMID * 15);
            int cc  = rem / 15;
            int wq  = rem - cc * 15;
            int hr  = h - 1 + r;
            const float* dwp = wd + 6 * cc;      // taps: valid regardless of hr
            TA[k] = *(const float2*)(dwp);       // d0[0], d0[1]
            TB[k] = *(const float2*)(dwp + 2);   // d0[2], d1[0]
            TC[k] = *(const float2*)(dwp + 4);   // d1[1], d1[2]
            if ((unsigned)hr < HH) {
                int ws0  = 4 * wq;
                int lcol = (wq == 0)  ? 0  : ws0 - 2;   // clamped, 8B-aligned
                int mcol = (wq == 14) ? 48 : ws0;       // clamped, 16B-aligned
                const float* p0 = x + (2 * cc) * CHW + hr * WW;
                const float* p1 = p0 + CHW;
                L0[k] = *(const float2*)(p0 + lcol);
                L1[k] = *(const float2*)(p1 + lcol);
                M0[k] = *(const float4*)(p0 + mcol);
                M1[k] = *(const float4*)(p1 + mcol);
            }
        }
    }

    // ---- stage 2: A1 weight staging (runs under x-load latency) ----
    // 4608 floats per og-group, contiguous in wc: float4 loads, scalar scatter
    // into padded 4-float slots swc[ol*WSTR + (cc*3+dh)*4 + k].
    #pragma unroll
    for (int k = 0; k < 5; ++k) {
        int q = tid + k * 256;          // quad index, 1152 total
        if (q < 1152) {
            float4 wv = *(const float4*)(wc + og * (OG * 288) + 4 * q);
            float vv[4] = {wv.x, wv.y, wv.z, wv.w};
            int r0 = 4 * q;
            #pragma unroll
            for (int e = 0; e < 4; ++e) {
                int r    = r0 + e;
                int ol   = r / 288;
                int rr   = r - ol * 288;      // cc*9 + dh*3 + kk
                int cc   = rr / 9;
                int rem2 = rr - cc * 9;
                int dh   = rem2 / 3;
                int kk   = rem2 - dh * 3;
                swc[ol * WSTR + (cc * 3 + dh) * 4 + kk] = vv[e];
            }
        }
    }

    // ---- stage 3: A2 compute t5 and write st5 ----
    #pragma unroll
    for (int k = 0; k < 6; ++k) {
        int idx = tid + k * 256;
        if (idx < 3 * CMID * 15) {
            int r   = idx / (CMID * 15);
            int rem = idx - r * (CMID * 15);
            int cc  = rem / 15;
            int wq  = rem - cc * 15;
            int ws0 = 4 * wq;
            float2 l0 = L0[k], l1 = L1[k];
            float4 m0 = M0[k], m1 = M1[k];
            if (wq == 0)  { l0 = make_float2(0.f, 0.f); l1 = make_float2(0.f, 0.f); }
            if (wq == 14) { m0 = make_float4(0.f, 0.f, 0.f, 0.f);
                            m1 = make_float4(0.f, 0.f, 0.f, 0.f); }
            float t0[6] = {l0.x, l0.y, m0.x, m0.y, m0.z, m0.w};
            float t1[6] = {l1.x, l1.y, m1.x, m1.y, m1.z, m1.w};
            float2 dA = TA[k], dB = TB[k], dC = TC[k];
            float v[4];
            #pragma unroll
            for (int q = 0; q < 4; ++q)
                v[q] = t0[q] * dA.x + t0[q + 1] * dA.y + t0[q + 2] * dB.x
                     + t1[q] * dB.y + t1[q + 1] * dC.x + t1[q + 2] * dC.y;
            if (wq == 0)  v[0] = 0.f;                              // wp = -1
            if (wq == 14) { v[1] = 0.f; v[2] = 0.f; v[3] = 0.f; }  // wp >= 56
            *(float4*)(st5 + (r * CMID + cc) * T5STR + ws0) =
                make_float4(v[0], v[1], v[2], v[3]);
        }
    }
    __syncthreads();

    // ---- phase B: 3x3 conv, 2 ol x 8 w per thread, cc split by ccq ----
    if (tid < 224) {
        const int ccq  = tid & 3;        // lane bits 0-1 -> shfl_xor reduce
        const int rest = tid >> 2;
        const int olg  = rest / 7;       // 0..7
        const int wt   = rest - olg * 7; // 0..6
        const int w0   = wt * 8;
        const int ol0  = olg * 2;

        float acc0[8] = {0, 0, 0, 0, 0, 0, 0, 0};
        float acc1[8] = {0, 0, 0, 0, 0, 0, 0, 0};
        const float* wb0 = swc + ol0 * WSTR;
        const float* wb1 = wb0 + WSTR;

        #pragma unroll
        for (int i = 0; i < 8; ++i) {
            int cc = ccq + 4 * i;  // ccq lanes: adjacent st5 rows -> +4 banks
            #pragma unroll
            for (int dh = 0; dh < 3; ++dh) {
                const float* trow = st5 + (dh * CMID + cc) * T5STR + w0;
                float4 a  = *(const float4*)trow;
                float4 b  = *(const float4*)(trow + 4);
                float2 c2 = *(const float2*)(trow + 8);
                float t[10] = {a.x, a.y, a.z, a.w, b.x, b.y, b.z, b.w, c2.x, c2.y};
                int wi = (cc * 3 + dh) * 4;
                float4 wv0 = *(const float4*)(wb0 + wi);
                float4 wv1 = *(const float4*)(wb1 + wi);
                #pragma unroll
                for (int j = 0; j < 8; ++j) {
                    acc0[j] += t[j] * wv0.x + t[j + 1] * wv0.y + t[j + 2] * wv0.z;
                    acc1[j] += t[j] * wv1.x + t[j + 1] * wv1.y + t[j + 2] * wv1.z;
                }
            }
        }

        #pragma unroll
        for (int j = 0; j < 8; ++j) {
            acc0[j] += __shfl_xor(acc0[j], 1);
            acc0[j] += __shfl_xor(acc0[j], 2);
            acc1[j] += __shfl_xor(acc1[j], 1);
            acc1[j] += __shfl_xor(acc1[j], 2);
        }

        if (ccq == 0) {
            int o0 = og * OG + ol0;
            float* p0 = out + (o0 * HH + h) * WW + w0;
            float* p1 = p0 + CHW;
            *(float4*)(p0)     = make_float4(acc0[0], acc0[1], acc0[2], acc0[3]);
            *(float4*)(p0 + 4) = make_float4(acc0[4], acc0[5], acc0[6], acc0[7]);
            *(float4*)(p1)     = make_float4(acc1[0], acc1[1], acc1[2], acc1[3]);
            *(float4*)(p1 + 4) = make_float4(acc1[4], acc1[5], acc1[6], acc1[7]);
        }
    }
}

extern "C" void kernel_launch(void* const* d_in, const int* in_sizes, int n_in,
                              void* d_out, int out_size, void* d_ws, size_t ws_size,
                              hipStream_t stream) {
    const float* x  = (const float*)d_in[0];
    const float* wc = (const float*)d_in[1];
    const float* wd = (const float*)d_in[2];
    float* out = (float*)d_out;
    dim3 grid(HH, CIN / OG);  // 56 x 4 = 224 blocks
    fused_dw_sum_conv<<<grid, 256, 0, stream>>>(x, wc, wd, out);
}